// Round 2
// baseline (120.957 us; speedup 1.0000x reference)
//
#include <hip/hip_runtime.h>
#include <hip/hip_bf16.h>

typedef float f32x4 __attribute__((ext_vector_type(4)));
typedef short bf16x8 __attribute__((ext_vector_type(8)));
typedef int   int4v  __attribute__((ext_vector_type(4)));

#define LOG2E 1.44269504088896340736f
#define LN2   0.693147180559945309417f

// ---------------------------------------------------------------------------
// Kernel 1: q = x@Wq+bq, k = x@Wk+bk (-> bf16 hi+lo pairs), v = x@Wv+bv (f32).
// 4 rows per block, 192 threads: wave m in {0,1,2} handles matrix m, f=lane.
// ---------------------------------------------------------------------------
__global__ __launch_bounds__(192) void k_qkv(
    const float* __restrict__ x,
    const float* __restrict__ Wq, const float* __restrict__ bq,
    const float* __restrict__ Wk, const float* __restrict__ bk,
    const float* __restrict__ Wv, const float* __restrict__ bv,
    __hip_bfloat16* __restrict__ qhi, __hip_bfloat16* __restrict__ qlo,
    __hip_bfloat16* __restrict__ khi, __hip_bfloat16* __restrict__ klo,
    float* __restrict__ vout)
{
    const int row0 = blockIdx.x * 4;           // rows = b*512 + i, [0,1024)
    __shared__ __align__(16) float xr[4][512];
    const int tid = threadIdx.x;

    for (int i = tid; i < 512; i += 192)       // 4 rows * 512 f32 = 512 float4
        ((f32x4*)&xr[0][0])[i] = ((const f32x4*)(x + (size_t)row0 * 512))[i];
    __syncthreads();

    const int m = tid >> 6, f = tid & 63;
    const float* W    = (m == 0) ? Wq : (m == 1) ? Wk : Wv;
    const float bias  = ((m == 0) ? bq : (m == 1) ? bk : bv)[f];
    float a[4];
    a[0] = a[1] = a[2] = a[3] = bias;
    #pragma unroll 8
    for (int d = 0; d < 512; ++d) {
        float w = W[(size_t)d * 64 + f];
        a[0] = fmaf(xr[0][d], w, a[0]);
        a[1] = fmaf(xr[1][d], w, a[1]);
        a[2] = fmaf(xr[2][d], w, a[2]);
        a[3] = fmaf(xr[3][d], w, a[3]);
    }
    if (m == 2) {
        #pragma unroll
        for (int r = 0; r < 4; ++r)
            vout[(size_t)(row0 + r) * 64 + f] = a[r];
    } else {
        __hip_bfloat16* hi = (m == 0) ? qhi : khi;
        __hip_bfloat16* lo = (m == 0) ? qlo : klo;
        #pragma unroll
        for (int r = 0; r < 4; ++r) {
            __hip_bfloat16 h = __float2bfloat16(a[r]);
            __hip_bfloat16 l = __float2bfloat16(a[r] - __bfloat162float(h));
            hi[(size_t)(row0 + r) * 64 + f] = h;
            lo[(size_t)(row0 + r) * 64 + f] = l;
        }
    }
}

// ---------------------------------------------------------------------------
// Kernel 2: per (b, i-tile 32, j-tile 32): for each shift s (=126-t) compute
// conv tile via MFMA on sliding windows of reversed zero-padded K rows.
// PASS 0: cheap hi*hi conv -> approximate max M~ (only needs +-1 accuracy).
// PASS 1: precise conv (qh*kh + qh*kl + ql*kh) -> sum 2^(a-M~), sum a.
// Merge 4 wave chunks; s[i][j] = ln2*(TA - 127*(M + log2(SE))).
// ---------------------------------------------------------------------------
__device__ __forceinline__ void extract8(const int (&dk)[8], int r, bf16x8 &out)
{
    union { int i[4]; bf16x8 v; } u;
    const int p2 = r >> 1;
    #pragma unroll
    for (int i = 0; i < 4; ++i) {
        if (r & 1) {
            unsigned lo32 = (unsigned)dk[p2 + i];
            unsigned hi32 = (unsigned)dk[p2 + i + 1];
            u.i[i] = (int)((lo32 >> 16) | (hi32 << 16)); // v_alignbit
        } else {
            u.i[i] = dk[p2 + i];
        }
    }
    out = u.v;
}

template<int PASS>
__device__ __forceinline__ void score_chunk(
    const __hip_bfloat16 (*__restrict__ ldsKh)[200],
    const __hip_bfloat16 (*__restrict__ ldsKl)[200],
    const float* __restrict__ t2,
    const bf16x8 (&afh)[2][2], const bf16x8 (&afl)[2][2],
    int s0, int s1, int lrow, int g,
    float (&mh)[16], float (&se)[16], float (&sa)[16])
{
    for (int s8 = s0; s8 < s1; s8 += 8) {
        f32x4 tt0 = *(const f32x4*)&t2[s8];
        f32x4 tt1 = *(const f32x4*)&t2[s8 + 4];
        int dkh[2][2][8], dkl[2][2][8];
        #pragma unroll
        for (int jh = 0; jh < 2; ++jh) {
            #pragma unroll
            for (int kc = 0; kc < 2; ++kc) {
                const int off = s8 + kc * 32 + g * 8;
                const int4v* kp = (const int4v*)&ldsKh[jh * 16 + lrow][off];
                int4v lo = kp[0];
                int4v hi = kp[1];
                #pragma unroll
                for (int i = 0; i < 4; ++i) {
                    dkh[jh][kc][i]     = lo[i];
                    dkh[jh][kc][4 + i] = hi[i];
                }
                if (PASS == 1) {
                    const int4v* kq = (const int4v*)&ldsKl[jh * 16 + lrow][off];
                    int4v lo2 = kq[0];
                    int4v hi2 = kq[1];
                    #pragma unroll
                    for (int i = 0; i < 4; ++i) {
                        dkl[jh][kc][i]     = lo2[i];
                        dkl[jh][kc][4 + i] = hi2[i];
                    }
                }
            }
        }
        #pragma unroll
        for (int r = 0; r < 8; ++r) {
            if (s8 + r < s1) {
                bf16x8 bfh[2][2], bfl[2][2];
                #pragma unroll
                for (int jh = 0; jh < 2; ++jh) {
                    #pragma unroll
                    for (int kc = 0; kc < 2; ++kc) {
                        extract8(dkh[jh][kc], r, bfh[jh][kc]);
                        if (PASS == 1) extract8(dkl[jh][kc], r, bfl[jh][kc]);
                    }
                }
                const f32x4 zf = {0.f, 0.f, 0.f, 0.f};
                f32x4 acc[2][2];
                #pragma unroll
                for (int ih = 0; ih < 2; ++ih)
                    #pragma unroll
                    for (int jh = 0; jh < 2; ++jh) {
                        f32x4 c = __builtin_amdgcn_mfma_f32_16x16x32_bf16(afh[ih][0], bfh[jh][0], zf, 0, 0, 0);
                        c = __builtin_amdgcn_mfma_f32_16x16x32_bf16(afh[ih][1], bfh[jh][1], c, 0, 0, 0);
                        if (PASS == 1) {
                            c = __builtin_amdgcn_mfma_f32_16x16x32_bf16(afh[ih][0], bfl[jh][0], c, 0, 0, 0);
                            c = __builtin_amdgcn_mfma_f32_16x16x32_bf16(afh[ih][1], bfl[jh][1], c, 0, 0, 0);
                            c = __builtin_amdgcn_mfma_f32_16x16x32_bf16(afl[ih][0], bfh[jh][0], c, 0, 0, 0);
                            c = __builtin_amdgcn_mfma_f32_16x16x32_bf16(afl[ih][1], bfh[jh][1], c, 0, 0, 0);
                        }
                        acc[ih][jh] = c;
                    }
                const float t2v = (r < 4) ? tt0[r & 3] : tt1[r & 3];
                #pragma unroll
                for (int ih = 0; ih < 2; ++ih)
                    #pragma unroll
                    for (int jh = 0; jh < 2; ++jh)
                        #pragma unroll
                        for (int rr = 0; rr < 4; ++rr) {
                            const int p = (ih * 2 + jh) * 4 + rr;
                            float av = acc[ih][jh][rr] * t2v;
                            if (PASS == 0) {
                                mh[p] = fmaxf(mh[p], av);
                            } else {
                                se[p] += exp2f(av - mh[p]);
                                sa[p] += av;
                            }
                        }
            }
        }
    }
}

__global__ __launch_bounds__(256, 2) void k_score(
    const __hip_bfloat16* __restrict__ qhi, const __hip_bfloat16* __restrict__ qlo,
    const __hip_bfloat16* __restrict__ khi, const __hip_bfloat16* __restrict__ klo,
    float* __restrict__ sout)
{
    const int jt = blockIdx.x, it = blockIdx.y, b = blockIdx.z;
    __shared__ __align__(16) __hip_bfloat16 ldsQ[2][32][72];
    __shared__ __align__(16) __hip_bfloat16 ldsK[2][32][200];
    __shared__ __align__(16) float t2[128];
    __shared__ __align__(16) float mbuf[3][1024];

    const int tid = threadIdx.x;

    { // zero both ldsK arrays (incl. pads): 2*32*200*2B = 6400 ints
        int* kz = (int*)&ldsK[0][0][0];
        #pragma unroll
        for (int i = 0; i < 25; ++i)
            kz[tid + i * 256] = 0;
    }
    { // stage Q tiles (hi, lo): each 32 rows x 64 bf16 = 256 int4
        int r = tid >> 3, c8 = (tid & 7) << 3;
        *(int4v*)&ldsQ[0][r][c8] =
            *(const int4v*)(qhi + ((size_t)(b * 512 + it * 32 + r) * 64 + c8));
        *(int4v*)&ldsQ[1][r][c8] =
            *(const int4v*)(qlo + ((size_t)(b * 512 + it * 32 + r) * 64 + c8));
    }
    if (tid < 127) { // scaler table indexed by shift s (t = 126 - s)
        int s = tid, t = 126 - s;
        float nd = (t < 64) ? (float)(t + 1) : (float)(127 - t);
        t2[s] = ((float)(t + 2) / nd) * LOG2E;
    }
    __syncthreads();
    { // stage K reversed: ldsK[h][r][126-c] = k{hi,lo}[j0+r][c]
        #pragma unroll
        for (int i = 0; i < 16; ++i) {
            int idx = tid + i * 256;                       // 4096 elems
            int h = idx >> 11;
            int rem = idx & 2047;
            int r = rem >> 6, c = rem & 63;
            const __hip_bfloat16* src = h ? klo : khi;
            ldsK[h][r][126 - c] = src[(size_t)(b * 512 + jt * 32 + r) * 64 + c];
        }
    }
    __syncthreads();

    const int wid = tid >> 6, lane = tid & 63;
    const int lrow = lane & 15, g = lane >> 4;

    bf16x8 afh[2][2], afl[2][2];
    #pragma unroll
    for (int ih = 0; ih < 2; ++ih)
        #pragma unroll
        for (int kc = 0; kc < 2; ++kc) {
            afh[ih][kc] = *(const bf16x8*)&ldsQ[0][ih * 16 + lrow][kc * 32 + g * 8];
            afl[ih][kc] = *(const bf16x8*)&ldsQ[1][ih * 16 + lrow][kc * 32 + g * 8];
        }

    const int s0 = wid * 32;
    const int s1 = (wid == 3) ? 127 : (s0 + 32);

    float mh[16], se[16], sa[16];
    #pragma unroll
    for (int p = 0; p < 16; ++p) { mh[p] = -3.0e38f; se[p] = 0.f; sa[p] = 0.f; }

    score_chunk<0>(ldsK[0], ldsK[1], t2, afh, afl, s0, s1, lrow, g, mh, se, sa);
    score_chunk<1>(ldsK[0], ldsK[1], t2, afh, afl, s0, s1, lrow, g, mh, se, sa);

    // sequential cross-wave merge of (max, sumexp2, sum-arg)
    for (int w = 0; w < 4; ++w) {
        if (wid == w) {
            #pragma unroll
            for (int p = 0; p < 16; ++p) {
                const int ih = p >> 3, jh = (p >> 2) & 1, rr = p & 3;
                const int il = ih * 16 + g * 4 + rr;
                const int jl = jh * 16 + lrow;
                const int pi = il * 32 + jl;
                if (w == 0) {
                    mbuf[0][pi] = mh[p]; mbuf[1][pi] = se[p]; mbuf[2][pi] = sa[p];
                } else {
                    float Mo = mbuf[0][pi];
                    float M  = fmaxf(Mo, mh[p]);
                    mbuf[0][pi] = M;
                    mbuf[1][pi] = mbuf[1][pi] * exp2f(Mo - M) + se[p] * exp2f(mh[p] - M);
                    mbuf[2][pi] += sa[p];
                }
            }
        }
        __syncthreads();
    }
    #pragma unroll
    for (int k4 = 0; k4 < 4; ++k4) {
        int pi = tid + k4 * 256;
        float M = mbuf[0][pi], SE = mbuf[1][pi], TA = mbuf[2][pi];
        float sv = LN2 * (TA - 127.0f * (M + log2f(SE)));
        int il = pi >> 5, jl = pi & 31;
        sout[(size_t)(b * 512 + it * 32 + il) * 512 + jt * 32 + jl] = sv;
    }
}

// ---------------------------------------------------------------------------
// Kernel 3: p = s @ v  (512-reduction), then out = p @ Wp + bp.
// 4 rows per block (one wave per row), thread = (row r, col l).
// ---------------------------------------------------------------------------
__global__ __launch_bounds__(256) void k_pv(
    const float* __restrict__ s, const float* __restrict__ v,
    const float* __restrict__ Wp, const float* __restrict__ bp,
    float* __restrict__ out)
{
    const int tid = threadIdx.x;
    const int l = tid & 63, r = tid >> 6;
    const int row = blockIdx.x * 4 + r;       // [0,1024)
    const int b = row >> 9;
    const float* srow = s + (size_t)row * 512;
    const float* vb   = v + (size_t)b * 512 * 64;
    float acc = 0.f;
    #pragma unroll 8
    for (int j = 0; j < 512; ++j)
        acc = fmaf(srow[j], vb[(size_t)j * 64 + l], acc);

    __shared__ float pb[4][64];
    pb[r][l] = acc;
    __syncthreads();

    float o = bp[l];
    #pragma unroll 8
    for (int jj = 0; jj < 64; ++jj)
        o = fmaf(pb[r][jj], Wp[(size_t)jj * 64 + l], o);
    out[(size_t)row * 64 + l] = o;
}

// ---------------------------------------------------------------------------
extern "C" void kernel_launch(void* const* d_in, const int* in_sizes, int n_in,
                              void* d_out, int out_size, void* d_ws, size_t ws_size,
                              hipStream_t stream)
{
    const float* x  = (const float*)d_in[0];
    const float* Wq = (const float*)d_in[1];
    const float* bq = (const float*)d_in[2];
    const float* Wk = (const float*)d_in[3];
    const float* bk = (const float*)d_in[4];
    const float* Wv = (const float*)d_in[5];
    const float* bv = (const float*)d_in[6];
    const float* Wp = (const float*)d_in[7];
    const float* bp = (const float*)d_in[8];
    float* out = (float*)d_out;

    char* ws = (char*)d_ws;
    __hip_bfloat16* qhi = (__hip_bfloat16*)(ws + 0 * 131072);
    __hip_bfloat16* qlo = (__hip_bfloat16*)(ws + 1 * 131072);
    __hip_bfloat16* khi = (__hip_bfloat16*)(ws + 2 * 131072);
    __hip_bfloat16* klo = (__hip_bfloat16*)(ws + 3 * 131072);
    float* vws = (float*)(ws + 4 * 131072);                 // 262144 B
    float* sws = (float*)(ws + 4 * 131072 + 262144);        // 2097152 B

    k_qkv<<<dim3(256), dim3(192), 0, stream>>>(x, Wq, bq, Wk, bk, Wv, bv,
                                               qhi, qlo, khi, klo, vws);
    k_score<<<dim3(16, 16, 2), dim3(256), 0, stream>>>(qhi, qlo, khi, klo, sws);
    k_pv<<<dim3(256), dim3(256), 0, stream>>>(sws, vws, Wp, bp, out);
}

// Round 4
// 74.151 us; speedup vs baseline: 1.6312x; 1.6312x over previous
//
#include <hip/hip_runtime.h>
#include <hip/hip_bf16.h>

typedef float f32x4 __attribute__((ext_vector_type(4)));
typedef _Float16 f16x8 __attribute__((ext_vector_type(8)));
typedef int   int4v  __attribute__((ext_vector_type(4)));

#define LOG2E 1.44269504088896340736f
#define LN2   0.693147180559945309417f

// ---------------------------------------------------------------------------
// Kernel 1: q = x@Wq+bq, k = x@Wk+bk (-> fp16), v = x@Wv+bv (f32).
// 4 rows per block, 192 threads: wave m in {0,1,2} handles matrix m, f=lane.
// ---------------------------------------------------------------------------
__global__ __launch_bounds__(192) void k_qkv(
    const float* __restrict__ x,
    const float* __restrict__ Wq, const float* __restrict__ bq,
    const float* __restrict__ Wk, const float* __restrict__ bk,
    const float* __restrict__ Wv, const float* __restrict__ bv,
    _Float16* __restrict__ qf, _Float16* __restrict__ kf,
    float* __restrict__ vout)
{
    const int row0 = blockIdx.x * 4;           // rows = b*512 + i, [0,1024)
    __shared__ __align__(16) float xr[4][512];
    const int tid = threadIdx.x;

    for (int i = tid; i < 512; i += 192)       // 4 rows * 512 f32 = 512 float4
        ((f32x4*)&xr[0][0])[i] = ((const f32x4*)(x + (size_t)row0 * 512))[i];
    __syncthreads();

    const int m = tid >> 6, f = tid & 63;
    const float* W    = (m == 0) ? Wq : (m == 1) ? Wk : Wv;
    const float bias  = ((m == 0) ? bq : (m == 1) ? bk : bv)[f];
    float a[4];
    a[0] = a[1] = a[2] = a[3] = bias;
    #pragma unroll 8
    for (int d = 0; d < 512; ++d) {
        float w = W[(size_t)d * 64 + f];
        a[0] = fmaf(xr[0][d], w, a[0]);
        a[1] = fmaf(xr[1][d], w, a[1]);
        a[2] = fmaf(xr[2][d], w, a[2]);
        a[3] = fmaf(xr[3][d], w, a[3]);
    }
    if (m == 2) {
        #pragma unroll
        for (int r = 0; r < 4; ++r)
            vout[(size_t)(row0 + r) * 64 + f] = a[r];
    } else {
        _Float16* dst = (m == 0) ? qf : kf;
        #pragma unroll
        for (int r = 0; r < 4; ++r)
            dst[(size_t)(row0 + r) * 64 + f] = (_Float16)a[r];
    }
}

// ---------------------------------------------------------------------------
// Kernel 2: per (b, i-tile 32, j-tile 16): for each shift s (=126-t) compute
// conv tile via fp16 MFMA on sliding windows of reversed zero-padded K rows.
// PASS 0: max of av; PASS 1: identical av -> sum 2^(av-M) (<=1 always), sum av.
// Merge 4 wave chunks; s[i][j] = ln2*(TA - 127*(M + log2(SE))).
// ---------------------------------------------------------------------------
__device__ __forceinline__ void extract8(const int (&dk)[8], int r, f16x8 &out)
{
    union { int i[4]; f16x8 v; } u;
    const int p2 = r >> 1;
    #pragma unroll
    for (int i = 0; i < 4; ++i) {
        if (r & 1) {
            unsigned lo32 = (unsigned)dk[p2 + i];
            unsigned hi32 = (unsigned)dk[p2 + i + 1];
            u.i[i] = (int)((lo32 >> 16) | (hi32 << 16)); // v_alignbit
        } else {
            u.i[i] = dk[p2 + i];
        }
    }
    out = u.v;
}

template<int PASS>
__device__ __forceinline__ void score_chunk(
    const _Float16 (*__restrict__ ldsK)[200],
    const float* __restrict__ t2,
    const f16x8 (&af)[2][2],
    int s0, int s1, int lrow, int g,
    float (&mh)[8], float (&se)[8], float (&sa)[8])
{
    for (int s8 = s0; s8 < s1; s8 += 8) {
        f32x4 tt0 = *(const f32x4*)&t2[s8];
        f32x4 tt1 = *(const f32x4*)&t2[s8 + 4];
        int dk[2][8];
        #pragma unroll
        for (int kc = 0; kc < 2; ++kc) {
            const int off = s8 + kc * 32 + g * 8;
            const int4v* kp = (const int4v*)&ldsK[lrow][off];
            int4v lo = kp[0];
            int4v hi = kp[1];
            #pragma unroll
            for (int i = 0; i < 4; ++i) {
                dk[kc][i]     = lo[i];
                dk[kc][4 + i] = hi[i];
            }
        }
        #pragma unroll
        for (int r = 0; r < 8; ++r) {
            if (s8 + r < s1) {
                f16x8 bfr[2];
                extract8(dk[0], r, bfr[0]);
                extract8(dk[1], r, bfr[1]);
                const f32x4 zf = {0.f, 0.f, 0.f, 0.f};
                f32x4 acc[2];
                #pragma unroll
                for (int ih = 0; ih < 2; ++ih) {
                    f32x4 c = __builtin_amdgcn_mfma_f32_16x16x32_f16(af[ih][0], bfr[0], zf, 0, 0, 0);
                    acc[ih]  = __builtin_amdgcn_mfma_f32_16x16x32_f16(af[ih][1], bfr[1], c, 0, 0, 0);
                }
                const float t2v = (r < 4) ? tt0[r & 3] : tt1[r & 3];
                #pragma unroll
                for (int ih = 0; ih < 2; ++ih)
                    #pragma unroll
                    for (int rr = 0; rr < 4; ++rr) {
                        const int p = ih * 4 + rr;
                        float av = acc[ih][rr] * t2v;
                        if (PASS == 0) {
                            mh[p] = fmaxf(mh[p], av);
                        } else {
                            se[p] += exp2f(av - mh[p]);
                            sa[p] += av;
                        }
                    }
            }
        }
    }
}

__global__ __launch_bounds__(256, 4) void k_score(
    const _Float16* __restrict__ qf,
    const _Float16* __restrict__ kf,
    float* __restrict__ sout)
{
    const int jt = blockIdx.x, it = blockIdx.y, b = blockIdx.z;
    __shared__ __align__(16) _Float16 ldsQ[32][72];
    __shared__ __align__(16) _Float16 ldsK[16][200];
    __shared__ __align__(16) float t2[128];
    __shared__ __align__(16) float mbuf[3][512];

    const int tid = threadIdx.x;

    { // zero ldsK (incl. pads): 16*200*2B = 1600 ints
        int* kz = (int*)&ldsK[0][0];
        #pragma unroll
        for (int i = 0; i < 7; ++i) {
            int idx = tid + i * 256;
            if (idx < 1600) kz[idx] = 0;
        }
    }
    { // stage Q tile: 32 rows x 64 fp16 = 256 int4
        int r = tid >> 3, c8 = (tid & 7) << 3;
        *(int4v*)&ldsQ[r][c8] =
            *(const int4v*)(qf + ((size_t)(b * 512 + it * 32 + r) * 64 + c8));
    }
    if (tid < 127) { // scaler table indexed by shift s (t = 126 - s)
        int s = tid, t = 126 - s;
        float nd = (t < 64) ? (float)(t + 1) : (float)(127 - t);
        t2[s] = ((float)(t + 2) / nd) * LOG2E;
    }
    __syncthreads();
    { // stage K reversed: ldsK[r][126-c] = kf[j0+r][c], 16*64 = 1024 elems
        int idx = tid;
        #pragma unroll
        for (int i = 0; i < 4; ++i) {
            int r = idx >> 6, c = idx & 63;
            ldsK[r][126 - c] = kf[(size_t)(b * 512 + jt * 16 + r) * 64 + c];
            idx += 256;
        }
    }
    __syncthreads();

    const int wid = tid >> 6, lane = tid & 63;
    const int lrow = lane & 15, g = lane >> 4;

    f16x8 af[2][2];
    #pragma unroll
    for (int ih = 0; ih < 2; ++ih)
        #pragma unroll
        for (int kc = 0; kc < 2; ++kc)
            af[ih][kc] = *(const f16x8*)&ldsQ[ih * 16 + lrow][kc * 32 + g * 8];

    const int s0 = wid * 32;
    const int s1 = (wid == 3) ? 127 : (s0 + 32);

    float mh[8], se[8], sa[8];
    #pragma unroll
    for (int p = 0; p < 8; ++p) { mh[p] = -3.0e38f; se[p] = 0.f; sa[p] = 0.f; }

    score_chunk<0>(ldsK, t2, af, s0, s1, lrow, g, mh, se, sa);
    score_chunk<1>(ldsK, t2, af, s0, s1, lrow, g, mh, se, sa);

    // sequential cross-wave merge of (max, sumexp2, sum-arg)
    for (int w = 0; w < 4; ++w) {
        if (wid == w) {
            #pragma unroll
            for (int p = 0; p < 8; ++p) {
                const int ih = p >> 2, rr = p & 3;
                const int il = ih * 16 + g * 4 + rr;
                const int jl = lrow;
                const int pi = il * 16 + jl;
                if (w == 0) {
                    mbuf[0][pi] = mh[p]; mbuf[1][pi] = se[p]; mbuf[2][pi] = sa[p];
                } else {
                    float Mo = mbuf[0][pi];
                    float M  = fmaxf(Mo, mh[p]);
                    mbuf[0][pi] = M;
                    mbuf[1][pi] = mbuf[1][pi] * exp2f(Mo - M) + se[p] * exp2f(mh[p] - M);
                    mbuf[2][pi] += sa[p];
                }
            }
        }
        __syncthreads();
    }
    #pragma unroll
    for (int k2 = 0; k2 < 2; ++k2) {
        int pi = tid + k2 * 256;
        float M = mbuf[0][pi], SE = mbuf[1][pi], TA = mbuf[2][pi];
        float sv = LN2 * (TA - 127.0f * (M + log2f(SE)));
        int il = pi >> 4, jl = pi & 15;
        sout[(size_t)(b * 512 + it * 32 + il) * 512 + jt * 16 + jl] = sv;
    }
}

// ---------------------------------------------------------------------------
// Kernel 3: p = s @ v  (512-reduction), then out = p @ Wp + bp.
// 4 rows per block (one wave per row), thread = (row r, col l).
// ---------------------------------------------------------------------------
__global__ __launch_bounds__(256) void k_pv(
    const float* __restrict__ s, const float* __restrict__ v,
    const float* __restrict__ Wp, const float* __restrict__ bp,
    float* __restrict__ out)
{
    const int tid = threadIdx.x;
    const int l = tid & 63, r = tid >> 6;
    const int row = blockIdx.x * 4 + r;       // [0,1024)
    const int b = row >> 9;
    const float* srow = s + (size_t)row * 512;
    const float* vb   = v + (size_t)b * 512 * 64;
    float acc = 0.f;
    #pragma unroll 8
    for (int j = 0; j < 512; ++j)
        acc = fmaf(srow[j], vb[(size_t)j * 64 + l], acc);

    __shared__ float pb[4][64];
    pb[r][l] = acc;
    __syncthreads();

    float o = bp[l];
    #pragma unroll 8
    for (int jj = 0; jj < 64; ++jj)
        o = fmaf(pb[r][jj], Wp[(size_t)jj * 64 + l], o);
    out[(size_t)row * 64 + l] = o;
}

// ---------------------------------------------------------------------------
extern "C" void kernel_launch(void* const* d_in, const int* in_sizes, int n_in,
                              void* d_out, int out_size, void* d_ws, size_t ws_size,
                              hipStream_t stream)
{
    const float* x  = (const float*)d_in[0];
    const float* Wq = (const float*)d_in[1];
    const float* bq = (const float*)d_in[2];
    const float* Wk = (const float*)d_in[3];
    const float* bk = (const float*)d_in[4];
    const float* Wv = (const float*)d_in[5];
    const float* bv = (const float*)d_in[6];
    const float* Wp = (const float*)d_in[7];
    const float* bp = (const float*)d_in[8];
    float* out = (float*)d_out;

    char* ws = (char*)d_ws;
    _Float16* qf = (_Float16*)(ws + 0 * 131072);
    _Float16* kf = (_Float16*)(ws + 1 * 131072);
    float* vws = (float*)(ws + 2 * 131072);                 // 262144 B
    float* sws = (float*)(ws + 2 * 131072 + 262144);        // 2097152 B

    k_qkv<<<dim3(256), dim3(192), 0, stream>>>(x, Wq, bq, Wk, bk, Wv, bv,
                                               qf, kf, vws);
    k_score<<<dim3(32, 16, 2), dim3(256), 0, stream>>>(qf, kf, sws);
    k_pv<<<dim3(256), dim3(256), 0, stream>>>(sws, vws, Wp, bp, out);
}